// Round 3
// baseline (1311.213 us; speedup 1.0000x reference)
//
#include <hip/hip_runtime.h>
#include <cstdio>
#include <cstdint>

#define N_TOK 16384
#define DIM   1024
#define NEXP  8
#define HID   2048

typedef __attribute__((ext_vector_type(8))) short bf16x8;
typedef __attribute__((ext_vector_type(4))) float f32x4;

__device__ inline ushort f2bf(float f) {
  uint32_t u = __float_as_uint(f);
  uint32_t r = (u + 0x7fffu + ((u >> 16) & 1u)) >> 16;
  return (ushort)r;
}

// async global->LDS, 16B per lane; LDS dest is wave-uniform base + lane*16
__device__ __forceinline__ void gload_lds16(const void* g, void* l) {
  __builtin_amdgcn_global_load_lds((const __attribute__((address_space(1))) void*)g,
                                   (__attribute__((address_space(3))) void*)l, 16, 0, 0);
}

// ---------------- x f32 -> bf16 pre-convert ----------------
__global__ __launch_bounds__(256) void xcvt_kernel(const float* __restrict__ x,
                                                   ushort* __restrict__ xb) {
  size_t i = (size_t)blockIdx.x * 256 + threadIdx.x;  // 8 elems/thread
  float4 v0 = *(const float4*)(x + i * 8);
  float4 v1 = *(const float4*)(x + i * 8 + 4);
  ushort4 a = { f2bf(v0.x), f2bf(v0.y), f2bf(v0.z), f2bf(v0.w) };
  ushort4 b = { f2bf(v1.x), f2bf(v1.y), f2bf(v1.z), f2bf(v1.w) };
  *(ushort4*)(xb + i * 8) = a;
  *(ushort4*)(xb + i * 8 + 4) = b;
}

// ---------------- router: fp32 logits, top-2, renormalized gates ----------------
__global__ __launch_bounds__(256) void router_kernel(
    const float* __restrict__ x, const float* __restrict__ rw,
    const float* __restrict__ rb, int* __restrict__ cnt,
    int* __restrict__ tok_e, float* __restrict__ tok_g) {
  __shared__ float wT[NEXP][DIM];
  for (int i = threadIdx.x; i < NEXP * DIM; i += 256) {
    int d = i >> 3, e = i & 7;
    wT[e][d] = rw[i];
  }
  __syncthreads();
  int wave = threadIdx.x >> 6, lane = threadIdx.x & 63;
  int t0 = blockIdx.x * 16 + wave * 4;
  for (int it = 0; it < 4; ++it) {
    int t = t0 + it;
    const float* xr = x + (size_t)t * DIM;
    float acc[NEXP];
#pragma unroll
    for (int e = 0; e < NEXP; ++e) acc[e] = 0.f;
#pragma unroll
    for (int j = 0; j < DIM / 64; ++j) {
      int d = lane + j * 64;
      float xv = xr[d];
#pragma unroll
      for (int e = 0; e < NEXP; ++e) acc[e] += xv * wT[e][d];
    }
    float lg[NEXP];
#pragma unroll
    for (int e = 0; e < NEXP; ++e) {
      float v = acc[e];
      for (int o = 32; o > 0; o >>= 1) v += __shfl_xor(v, o);
      lg[e] = v + rb[e];
    }
    int i0 = 0; float m0 = lg[0];
#pragma unroll
    for (int e = 1; e < NEXP; ++e) if (lg[e] > m0) { m0 = lg[e]; i0 = e; }
    int i1 = -1; float m1 = -3.4e38f;
#pragma unroll
    for (int e = 0; e < NEXP; ++e) if (e != i0 && lg[e] > m1) { m1 = lg[e]; i1 = e; }
    float g0 = 1.f / (1.f + expf(m1 - m0));
    float g1 = 1.f - g0;
    if (lane == 0) {
      tok_e[2 * t] = i0; tok_e[2 * t + 1] = i1;
      tok_g[2 * t] = g0; tok_g[2 * t + 1] = g1;
      atomicAdd(&cnt[i0], 1); atomicAdd(&cnt[i1], 1);
    }
  }
}

__global__ void scan_kernel(const int* __restrict__ cnt, int* __restrict__ offs,
                            int* __restrict__ cursor) {
  if (threadIdx.x == 0) {
    int s = 0;
    for (int e = 0; e < NEXP; ++e) { offs[e] = s; cursor[e] = s; s += cnt[e]; }
    offs[NEXP] = s;
  }
}

__global__ __launch_bounds__(256) void gather_kernel(
    const int* __restrict__ tok_e, const float* __restrict__ tok_g,
    int* __restrict__ cursor, int* __restrict__ slot_token,
    float* __restrict__ slot_gate) {
  int t = blockIdx.x * 256 + threadIdx.x;
  if (t >= N_TOK) return;
#pragma unroll
  for (int k = 0; k < 2; ++k) {
    int e = tok_e[2 * t + k];
    int s = atomicAdd(&cursor[e], 1);
    slot_token[s] = t;
    slot_gate[s] = tok_g[2 * t + k];
  }
}

// ---------------- transpose + f32->bf16 convert (per expert) ----------------
template <int R, int C>
__global__ __launch_bounds__(256) void transpose_cvt(const float* __restrict__ src,
                                                     ushort* __restrict__ dst) {
  __shared__ float tile[64][65];
  int e = blockIdx.z;
  const float* s = src + (size_t)e * R * C;
  ushort* d = dst + (size_t)e * R * C;
  int r0 = blockIdx.y * 64, c0 = blockIdx.x * 64;
#pragma unroll
  for (int i = 0; i < 16; ++i) {
    int idx = i * 256 + threadIdx.x;
    int r = idx >> 6, c = idx & 63;
    tile[r][c] = s[(size_t)(r0 + r) * C + c0 + c];
  }
  __syncthreads();
#pragma unroll
  for (int i = 0; i < 16; ++i) {
    int idx = i * 256 + threadIdx.x;
    int orow = idx >> 6, oc = idx & 63;
    d[(size_t)(c0 + orow) * R + r0 + oc] = f2bf(tile[oc][orow]);
  }
}

// =============== 256x256 grouped GEMM, 8 waves, BK=64, dbuf prefetch ===============
// gemm1: h = relu(x_gather @ w1T^T + b1)
__global__ __launch_bounds__(512, 2) void gemm1_kernel(
    const ushort* __restrict__ xb, const ushort* __restrict__ w1T,
    const float* __restrict__ b1, const int* __restrict__ offs,
    const int* __restrict__ slot_token, ushort* __restrict__ h) {
  // bijective XCD swizzle: nwg = 8*64*8 = 4096; each XCD gets one expert (512 blocks)
  int flat = blockIdx.x;
  int swz = (flat & 7) * 512 + (flat >> 3);
  int e = swz >> 9;
  int rem = swz & 511;
  int mt = rem >> 3;
  int nt = rem & 7;
  int off = offs[e];
  int cn = offs[e + 1] - off;
  if (mt * 256 >= cn) return;

  __shared__ __align__(16) ushort Ab[2 * 256 * 64];
  __shared__ __align__(16) ushort Bb[2 * 256 * 64];
  __shared__ int toks[256];
  int tid = threadIdx.x;
  if (tid < 256) {
    int r = mt * 256 + tid;
    toks[tid] = slot_token[off + (r < cn ? r : 0)];
  }
  __syncthreads();
  int wave = tid >> 6, lane = tid & 63;
  int wm = (wave >> 2) * 128, wn = (wave & 3) * 64;

  // staging: chunk c covers rows c*64 + wave*8 + (lane>>3), col (lane&7)*8
  const ushort* Bsrc = w1T + (size_t)e * HID * DIM + (size_t)(nt * 256) * DIM;
  int colel = (lane & 7) * 8;
  const ushort* agp[4];
  const ushort* bgp[4];
  int ldso[4];
#pragma unroll
  for (int c = 0; c < 4; ++c) {
    int row = c * 64 + wave * 8 + (lane >> 3);
    agp[c] = xb + (size_t)toks[row] * DIM + colel;
    bgp[c] = Bsrc + (size_t)row * DIM + colel;
    ldso[c] = (c * 64 + wave * 8) * 64;  // wave-uniform LDS base (ushort idx)
  }
  f32x4 acc[8][4];
#pragma unroll
  for (int i = 0; i < 8; ++i)
#pragma unroll
    for (int j = 0; j < 4; ++j) acc[i][j] = (f32x4){0.f, 0.f, 0.f, 0.f};

  auto stage = [&](int buf) {
#pragma unroll
    for (int c = 0; c < 4; ++c) {
      gload_lds16(agp[c], &Ab[buf * 16384 + ldso[c]]);
      gload_lds16(bgp[c], &Bb[buf * 16384 + ldso[c]]);
      agp[c] += 64; bgp[c] += 64;
    }
  };
  auto compute = [&](int buf) {
    const ushort* Abuf = &Ab[buf * 16384];
    const ushort* Bbuf = &Bb[buf * 16384];
#pragma unroll
    for (int kk = 0; kk < 2; ++kk) {
      int colb = kk * 32 + (lane >> 4) * 8;
      bf16x8 a[8], b[4];
#pragma unroll
      for (int mi = 0; mi < 8; ++mi)
        a[mi] = *(const bf16x8*)&Abuf[(wm + mi * 16 + (lane & 15)) * 64 + colb];
#pragma unroll
      for (int ni = 0; ni < 4; ++ni)
        b[ni] = *(const bf16x8*)&Bbuf[(wn + ni * 16 + (lane & 15)) * 64 + colb];
#pragma unroll
      for (int mi = 0; mi < 8; ++mi)
#pragma unroll
        for (int ni = 0; ni < 4; ++ni)
          acc[mi][ni] = __builtin_amdgcn_mfma_f32_16x16x32_bf16(a[mi], b[ni], acc[mi][ni], 0, 0, 0);
    }
  };

  stage(0);
  __syncthreads();
  int buf = 0;
  for (int kt = 0; kt < DIM / 64 - 1; ++kt) {
    stage(buf ^ 1);
    compute(buf);
    __syncthreads();
    buf ^= 1;
  }
  compute(buf);

  int ln = lane & 15, lg4 = (lane >> 4) * 4;
#pragma unroll
  for (int ni = 0; ni < 4; ++ni) {
    int col = nt * 256 + wn + ni * 16 + ln;
    float bias = b1[(size_t)e * HID + col];
#pragma unroll
    for (int mi = 0; mi < 8; ++mi) {
#pragma unroll
      for (int rg = 0; rg < 4; ++rg) {
        int r = mt * 256 + wm + mi * 16 + lg4 + rg;
        if (r < cn) {
          float v = acc[mi][ni][rg] + bias;
          h[(size_t)(off + r) * HID + col] = f2bf(fmaxf(v, 0.f));
        }
      }
    }
  }
}

// gemm2: out[token] += gate * (h @ w2T^T + b2)
__global__ __launch_bounds__(512, 2) void gemm2_kernel(
    const ushort* __restrict__ h, const ushort* __restrict__ w2T,
    const float* __restrict__ b2, const int* __restrict__ offs,
    const int* __restrict__ slot_token, const float* __restrict__ slot_gate,
    float* __restrict__ out) {
  // bijective XCD swizzle: nwg = 4*64*8 = 2048; each XCD gets one expert (256 blocks)
  int flat = blockIdx.x;
  int swz = (flat & 7) * 256 + (flat >> 3);
  int e = swz >> 8;
  int rem = swz & 255;
  int mt = rem >> 2;
  int nt = rem & 3;
  int off = offs[e];
  int cn = offs[e + 1] - off;
  if (mt * 256 >= cn) return;

  __shared__ __align__(16) ushort Ab[2 * 256 * 64];
  __shared__ __align__(16) ushort Bb[2 * 256 * 64];
  __shared__ int toks[256];
  __shared__ float gts[256];
  int tid = threadIdx.x;
  if (tid < 256) {
    int r = mt * 256 + tid;
    int s = off + (r < cn ? r : 0);
    toks[tid] = slot_token[s];
    gts[tid] = slot_gate[s];
  }
  __syncthreads();
  int wave = tid >> 6, lane = tid & 63;
  int wm = (wave >> 2) * 128, wn = (wave & 3) * 64;

  const ushort* Bsrc = w2T + (size_t)e * DIM * HID + (size_t)(nt * 256) * HID;
  int colel = (lane & 7) * 8;
  const ushort* agp[4];
  const ushort* bgp[4];
  int ldso[4];
#pragma unroll
  for (int c = 0; c < 4; ++c) {
    int row = c * 64 + wave * 8 + (lane >> 3);
    int rr = mt * 256 + row; rr = rr < cn ? rr : 0;
    agp[c] = h + (size_t)(off + rr) * HID + colel;
    bgp[c] = Bsrc + (size_t)row * HID + colel;
    ldso[c] = (c * 64 + wave * 8) * 64;
  }
  f32x4 acc[8][4];
#pragma unroll
  for (int i = 0; i < 8; ++i)
#pragma unroll
    for (int j = 0; j < 4; ++j) acc[i][j] = (f32x4){0.f, 0.f, 0.f, 0.f};

  auto stage = [&](int buf) {
#pragma unroll
    for (int c = 0; c < 4; ++c) {
      gload_lds16(agp[c], &Ab[buf * 16384 + ldso[c]]);
      gload_lds16(bgp[c], &Bb[buf * 16384 + ldso[c]]);
      agp[c] += 64; bgp[c] += 64;
    }
  };
  auto compute = [&](int buf) {
    const ushort* Abuf = &Ab[buf * 16384];
    const ushort* Bbuf = &Bb[buf * 16384];
#pragma unroll
    for (int kk = 0; kk < 2; ++kk) {
      int colb = kk * 32 + (lane >> 4) * 8;
      bf16x8 a[8], b[4];
#pragma unroll
      for (int mi = 0; mi < 8; ++mi)
        a[mi] = *(const bf16x8*)&Abuf[(wm + mi * 16 + (lane & 15)) * 64 + colb];
#pragma unroll
      for (int ni = 0; ni < 4; ++ni)
        b[ni] = *(const bf16x8*)&Bbuf[(wn + ni * 16 + (lane & 15)) * 64 + colb];
#pragma unroll
      for (int mi = 0; mi < 8; ++mi)
#pragma unroll
        for (int ni = 0; ni < 4; ++ni)
          acc[mi][ni] = __builtin_amdgcn_mfma_f32_16x16x32_bf16(a[mi], b[ni], acc[mi][ni], 0, 0, 0);
    }
  };

  stage(0);
  __syncthreads();
  int buf = 0;
  for (int kt = 0; kt < HID / 64 - 1; ++kt) {
    stage(buf ^ 1);
    compute(buf);
    __syncthreads();
    buf ^= 1;
  }
  compute(buf);

  int ln = lane & 15, lg4 = (lane >> 4) * 4;
#pragma unroll
  for (int ni = 0; ni < 4; ++ni) {
    int col = nt * 256 + wn + ni * 16 + ln;
    float bias = b2[(size_t)e * DIM + col];
#pragma unroll
    for (int mi = 0; mi < 8; ++mi) {
#pragma unroll
      for (int rg = 0; rg < 4; ++rg) {
        int rl = wm + mi * 16 + lg4 + rg;
        int r = mt * 256 + rl;
        if (r < cn) {
          float v = gts[rl] * (acc[mi][ni][rg] + bias);
          atomicAdd(&out[(size_t)toks[rl] * DIM + col], v);
        }
      }
    }
  }
}

extern "C" void kernel_launch(void* const* d_in, const int* in_sizes, int n_in,
                              void* d_out, int out_size, void* d_ws, size_t ws_size,
                              hipStream_t stream) {
  const float* x  = (const float*)d_in[0];
  const float* rw = (const float*)d_in[1];
  const float* rb = (const float*)d_in[2];
  const float* w1 = (const float*)d_in[3];
  const float* b1 = (const float*)d_in[4];
  const float* w2 = (const float*)d_in[5];
  const float* b2 = (const float*)d_in[6];
  float* out = (float*)d_out;
  char* ws = (char*)d_ws;

  // workspace layout (xb aliases w2T: xb dead after gemm1, w2T created after)
  const size_t o_ctrl = 0;
  const size_t o_toke = 256;
  const size_t o_tokg = o_toke + 131072;
  const size_t o_stok = o_tokg + 131072;
  const size_t o_sgat = o_stok + 131072;
  const size_t o_xb   = o_sgat + 131072;
  const size_t o_w1T  = o_xb + (size_t)N_TOK * DIM * 2;
  const size_t o_h    = o_w1T + (size_t)NEXP * HID * DIM * 2;
  const size_t required = o_h + (size_t)N_TOK * 2 * HID * 2;  // ~202 MB
  if (ws_size < required) {
    fprintf(stderr, "kernel_launch: ws too small: have %zu need %zu\n", ws_size, required);
    return;
  }
  int* cnt        = (int*)(ws + o_ctrl);
  int* cursor     = cnt + 8;
  int* offs       = cnt + 16;
  int* tok_e      = (int*)(ws + o_toke);
  float* tok_g    = (float*)(ws + o_tokg);
  int* slot_token = (int*)(ws + o_stok);
  float* slot_gate= (float*)(ws + o_sgat);
  ushort* xb      = (ushort*)(ws + o_xb);
  ushort* w2T     = (ushort*)(ws + o_xb);   // aliased with xb
  ushort* w1T     = (ushort*)(ws + o_w1T);
  ushort* hbuf    = (ushort*)(ws + o_h);

  hipMemsetAsync(d_out, 0, (size_t)out_size * 4, stream);
  hipMemsetAsync(ws + o_ctrl, 0, 64, stream);

  xcvt_kernel<<<N_TOK * DIM / 8 / 256, 256, 0, stream>>>(x, xb);
  transpose_cvt<DIM, HID><<<dim3(HID / 64, DIM / 64, NEXP), 256, 0, stream>>>(w1, w1T);

  router_kernel<<<N_TOK / 16, 256, 0, stream>>>(x, rw, rb, cnt, tok_e, tok_g);
  scan_kernel<<<1, 64, 0, stream>>>(cnt, offs, cursor);
  gather_kernel<<<N_TOK / 256, 256, 0, stream>>>(tok_e, tok_g, cursor, slot_token, slot_gate);

  gemm1_kernel<<<8 * 64 * NEXP, 512, 0, stream>>>(xb, w1T, b1, offs, slot_token, hbuf);

  // xb dead; build w2T in its place: w2 [E][H][D] -> w2T [E][D][H]
  transpose_cvt<HID, DIM><<<dim3(DIM / 64, HID / 64, NEXP), 256, 0, stream>>>(w2, w2T);

  gemm2_kernel<<<4 * 64 * NEXP, 512, 0, stream>>>(hbuf, w2T, b2, offs, slot_token, slot_gate, out);
}

// Round 4
// 1119.676 us; speedup vs baseline: 1.1711x; 1.1711x over previous
//
#include <hip/hip_runtime.h>
#include <cstdio>
#include <cstdint>

#define N_TOK 16384
#define DIM   1024
#define NEXP  8
#define HID   2048
#define BK    32

typedef __attribute__((ext_vector_type(8))) short bf16x8;
typedef __attribute__((ext_vector_type(4))) float f32x4;

__device__ inline ushort f2bf(float f) {
  uint32_t u = __float_as_uint(f);
  uint32_t r = (u + 0x7fffu + ((u >> 16) & 1u)) >> 16;
  return (ushort)r;
}

// async global->LDS, 16B per lane; LDS dest is wave-uniform base + lane*16
__device__ __forceinline__ void gload_lds16(const void* g, void* l) {
  __builtin_amdgcn_global_load_lds((const __attribute__((address_space(1))) void*)g,
                                   (__attribute__((address_space(3))) void*)l, 16, 0, 0);
}

// ---------------- x f32 -> bf16 pre-convert ----------------
__global__ __launch_bounds__(256) void xcvt_kernel(const float* __restrict__ x,
                                                   ushort* __restrict__ xb) {
  size_t i = (size_t)blockIdx.x * 256 + threadIdx.x;
  float4 v0 = *(const float4*)(x + i * 8);
  float4 v1 = *(const float4*)(x + i * 8 + 4);
  ushort4 a = { f2bf(v0.x), f2bf(v0.y), f2bf(v0.z), f2bf(v0.w) };
  ushort4 b = { f2bf(v1.x), f2bf(v1.y), f2bf(v1.z), f2bf(v1.w) };
  *(ushort4*)(xb + i * 8) = a;
  *(ushort4*)(xb + i * 8 + 4) = b;
}

// ---------------- router ----------------
__global__ __launch_bounds__(256) void router_kernel(
    const float* __restrict__ x, const float* __restrict__ rw,
    const float* __restrict__ rb, int* __restrict__ cnt,
    int* __restrict__ tok_e, float* __restrict__ tok_g) {
  __shared__ float wT[NEXP][DIM];
  for (int i = threadIdx.x; i < NEXP * DIM; i += 256) {
    int d = i >> 3, e = i & 7;
    wT[e][d] = rw[i];
  }
  __syncthreads();
  int wave = threadIdx.x >> 6, lane = threadIdx.x & 63;
  int t0 = blockIdx.x * 16 + wave * 4;
  for (int it = 0; it < 4; ++it) {
    int t = t0 + it;
    const float* xr = x + (size_t)t * DIM;
    float acc[NEXP];
#pragma unroll
    for (int e = 0; e < NEXP; ++e) acc[e] = 0.f;
#pragma unroll
    for (int j = 0; j < DIM / 64; ++j) {
      int d = lane + j * 64;
      float xv = xr[d];
#pragma unroll
      for (int e = 0; e < NEXP; ++e) acc[e] += xv * wT[e][d];
    }
    float lg[NEXP];
#pragma unroll
    for (int e = 0; e < NEXP; ++e) {
      float v = acc[e];
      for (int o = 32; o > 0; o >>= 1) v += __shfl_xor(v, o);
      lg[e] = v + rb[e];
    }
    int i0 = 0; float m0 = lg[0];
#pragma unroll
    for (int e = 1; e < NEXP; ++e) if (lg[e] > m0) { m0 = lg[e]; i0 = e; }
    int i1 = -1; float m1 = -3.4e38f;
#pragma unroll
    for (int e = 0; e < NEXP; ++e) if (e != i0 && lg[e] > m1) { m1 = lg[e]; i1 = e; }
    float g0 = 1.f / (1.f + expf(m1 - m0));
    float g1 = 1.f - g0;
    if (lane == 0) {
      tok_e[2 * t] = i0; tok_e[2 * t + 1] = i1;
      tok_g[2 * t] = g0; tok_g[2 * t + 1] = g1;
      atomicAdd(&cnt[i0], 1); atomicAdd(&cnt[i1], 1);
    }
  }
}

__global__ void scan_kernel(const int* __restrict__ cnt, int* __restrict__ offs,
                            int* __restrict__ cursor) {
  if (threadIdx.x == 0) {
    int s = 0;
    for (int e = 0; e < NEXP; ++e) { offs[e] = s; cursor[e] = s; s += cnt[e]; }
    offs[NEXP] = s;
  }
}

__global__ __launch_bounds__(256) void gather_kernel(
    const int* __restrict__ tok_e, const float* __restrict__ tok_g,
    int* __restrict__ cursor, int* __restrict__ slot_token,
    float* __restrict__ slot_gate) {
  int t = blockIdx.x * 256 + threadIdx.x;
  if (t >= N_TOK) return;
#pragma unroll
  for (int k = 0; k < 2; ++k) {
    int e = tok_e[2 * t + k];
    int s = atomicAdd(&cursor[e], 1);
    slot_token[s] = t;
    slot_gate[s] = tok_g[2 * t + k];
  }
}

// ---------------- transpose + f32->bf16 convert (per expert) ----------------
template <int R, int C>
__global__ __launch_bounds__(256) void transpose_cvt(const float* __restrict__ src,
                                                     ushort* __restrict__ dst) {
  __shared__ float tile[64][65];
  int e = blockIdx.z;
  const float* s = src + (size_t)e * R * C;
  ushort* d = dst + (size_t)e * R * C;
  int r0 = blockIdx.y * 64, c0 = blockIdx.x * 64;
#pragma unroll
  for (int i = 0; i < 16; ++i) {
    int idx = i * 256 + threadIdx.x;
    int r = idx >> 6, c = idx & 63;
    tile[r][c] = s[(size_t)(r0 + r) * C + c0 + c];
  }
  __syncthreads();
#pragma unroll
  for (int i = 0; i < 16; ++i) {
    int idx = i * 256 + threadIdx.x;
    int orow = idx >> 6, oc = idx & 63;
    d[(size_t)(c0 + orow) * R + r0 + oc] = f2bf(tile[oc][orow]);
  }
}

// =============== 256x256 grouped GEMM, 8 waves, BK=32, 4-buf depth-3 pipeline ===============
// LDS per buf: A[256][32] (16 KB) then B[256][32] (16 KB). Swizzle: byte col ^= ((row>>1)&3)<<4.
// Staged with linear LDS dest + pre-swizzled GLOBAL source col (involution, rule 21).

#define WAITV(N) asm volatile("s_waitcnt vmcnt(" #N ")" ::: "memory")
#define PBAR()  do { __builtin_amdgcn_s_barrier(); __builtin_amdgcn_sched_barrier(0); } while (0)

// gemm1: h = relu(x_gather @ w1T^T + b1)   K = DIM -> T = 32 tiles
__global__ __launch_bounds__(512, 2) void gemm1_kernel(
    const ushort* __restrict__ xb, const ushort* __restrict__ w1T,
    const float* __restrict__ b1, const int* __restrict__ offs,
    const int* __restrict__ slot_token, ushort* __restrict__ h) {
  int flat = blockIdx.x;                     // nwg = 8*64*8 = 4096
  int swz = (flat & 7) * 512 + (flat >> 3);  // XCD x -> expert x
  int e = swz >> 9;
  int rem = swz & 511;
  int mt = rem >> 3;
  int nt = rem & 7;
  int off = offs[e];
  int cn = offs[e + 1] - off;
  if (mt * 256 >= cn) return;

  __shared__ __align__(16) ushort AB[4 * 16384];  // 128 KB
  __shared__ int toks[256];
  int tid = threadIdx.x;
  if (tid < 256) {
    int r = mt * 256 + tid;
    toks[tid] = slot_token[off + (r < cn ? r : 0)];
  }
  __syncthreads();
  int wave = tid >> 6, lane = tid & 63;
  int wm = (wave >> 2) * 128, wn = (wave & 3) * 64;

  // staging: chunk c in {0,1}: row = c*128 + wave*16 + (lane>>2); 16B at swizzled col
  const ushort* Bsrc = w1T + (size_t)e * HID * DIM + (size_t)(nt * 256) * DIM;
  int colsw = ((lane & 3) ^ ((lane >> 3) & 3)) * 8;  // pre-swizzled source col (elems)
  int r0 = wave * 16 + (lane >> 2);
  const ushort* ag0 = xb + (size_t)toks[r0] * DIM + colsw;
  const ushort* ag1 = xb + (size_t)toks[128 + r0] * DIM + colsw;
  const ushort* bg0 = Bsrc + (size_t)r0 * DIM + colsw;
  const ushort* bg1 = Bsrc + (size_t)(128 + r0) * DIM + colsw;
  int ldsA0 = (wave * 16) * BK;            // wave-uniform LDS bases (ushort idx)
  int ldsA1 = (128 + wave * 16) * BK;
  int ldsB0 = 8192 + ldsA0;
  int ldsB1 = 8192 + ldsA1;

  f32x4 acc[8][4];
#pragma unroll
  for (int i = 0; i < 8; ++i)
#pragma unroll
    for (int j = 0; j < 4; ++j) acc[i][j] = (f32x4){0.f, 0.f, 0.f, 0.f};

  // read offset: row_local = lane&15, k-slot = lane>>4, swizzled
  int rdo = (lane & 15) * 64 + ((((lane >> 4) & 3) << 4) ^ ((((lane & 15) >> 1) & 3) << 4));

  auto stage = [&](int buf) {
    ushort* lb = &AB[buf * 16384];
    gload_lds16(ag0, lb + ldsA0); ag0 += BK;
    gload_lds16(ag1, lb + ldsA1); ag1 += BK;
    gload_lds16(bg0, lb + ldsB0); bg0 += BK;
    gload_lds16(bg1, lb + ldsB1); bg1 += BK;
  };
  auto compute = [&](int buf) {
    const char* base = (const char*)AB + (size_t)buf * 32768;
    bf16x8 a[8], b[4];
#pragma unroll
    for (int mi = 0; mi < 8; ++mi)
      a[mi] = *(const bf16x8*)(base + (wm + mi * 16) * 64 + rdo);
#pragma unroll
    for (int ni = 0; ni < 4; ++ni)
      b[ni] = *(const bf16x8*)(base + 16384 + (wn + ni * 16) * 64 + rdo);
#pragma unroll
    for (int mi = 0; mi < 8; ++mi)
#pragma unroll
      for (int ni = 0; ni < 4; ++ni)
        acc[mi][ni] = __builtin_amdgcn_mfma_f32_16x16x32_bf16(a[mi], b[ni], acc[mi][ni], 0, 0, 0);
  };

  const int T = DIM / BK;  // 32, divisible by 4
  stage(0); stage(1); stage(2);
  for (int t4 = 0; t4 < T - 4; t4 += 4) {
    WAITV(8); PBAR(); stage(3); compute(0);
    WAITV(8); PBAR(); stage(0); compute(1);
    WAITV(8); PBAR(); stage(1); compute(2);
    WAITV(8); PBAR(); stage(2); compute(3);
  }
  WAITV(8); PBAR(); stage(3); compute(0);  // t=T-4, stages tile T-1
  WAITV(8); PBAR(); compute(1);            // t=T-3
  WAITV(4); PBAR(); compute(2);            // t=T-2
  WAITV(0); PBAR(); compute(3);            // t=T-1

  int ln = lane & 15, lg4 = (lane >> 4) * 4;
#pragma unroll
  for (int ni = 0; ni < 4; ++ni) {
    int col = nt * 256 + wn + ni * 16 + ln;
    float bias = b1[(size_t)e * HID + col];
#pragma unroll
    for (int mi = 0; mi < 8; ++mi) {
#pragma unroll
      for (int rg = 0; rg < 4; ++rg) {
        int r = mt * 256 + wm + mi * 16 + lg4 + rg;
        if (r < cn) {
          float v = acc[mi][ni][rg] + bias;
          h[(size_t)(off + r) * HID + col] = f2bf(fmaxf(v, 0.f));
        }
      }
    }
  }
}

// gemm2: out[token] += gate * (h @ w2T^T + b2)   K = HID -> T = 64 tiles
__global__ __launch_bounds__(512, 2) void gemm2_kernel(
    const ushort* __restrict__ h, const ushort* __restrict__ w2T,
    const float* __restrict__ b2, const int* __restrict__ offs,
    const int* __restrict__ slot_token, const float* __restrict__ slot_gate,
    float* __restrict__ out) {
  int flat = blockIdx.x;                     // nwg = 4*64*8 = 2048
  int swz = (flat & 7) * 256 + (flat >> 3);  // XCD x -> expert x
  int e = swz >> 8;
  int rem = swz & 255;
  int mt = rem >> 2;
  int nt = rem & 3;
  int off = offs[e];
  int cn = offs[e + 1] - off;
  if (mt * 256 >= cn) return;

  __shared__ __align__(16) ushort AB[4 * 16384];  // 128 KB
  __shared__ int toks[256];
  __shared__ float gts[256];
  int tid = threadIdx.x;
  if (tid < 256) {
    int r = mt * 256 + tid;
    int s = off + (r < cn ? r : 0);
    toks[tid] = slot_token[s];
    gts[tid] = slot_gate[s];
  }
  __syncthreads();
  int wave = tid >> 6, lane = tid & 63;
  int wm = (wave >> 2) * 128, wn = (wave & 3) * 64;

  const ushort* Bsrc = w2T + (size_t)e * DIM * HID + (size_t)(nt * 256) * HID;
  int colsw = ((lane & 3) ^ ((lane >> 3) & 3)) * 8;
  int r0 = wave * 16 + (lane >> 2);
  int ra0 = mt * 256 + r0;       ra0 = ra0 < cn ? ra0 : 0;
  int ra1 = mt * 256 + 128 + r0; ra1 = ra1 < cn ? ra1 : 0;
  const ushort* ag0 = h + (size_t)(off + ra0) * HID + colsw;
  const ushort* ag1 = h + (size_t)(off + ra1) * HID + colsw;
  const ushort* bg0 = Bsrc + (size_t)r0 * HID + colsw;
  const ushort* bg1 = Bsrc + (size_t)(128 + r0) * HID + colsw;
  int ldsA0 = (wave * 16) * BK;
  int ldsA1 = (128 + wave * 16) * BK;
  int ldsB0 = 8192 + ldsA0;
  int ldsB1 = 8192 + ldsA1;

  f32x4 acc[8][4];
#pragma unroll
  for (int i = 0; i < 8; ++i)
#pragma unroll
    for (int j = 0; j < 4; ++j) acc[i][j] = (f32x4){0.f, 0.f, 0.f, 0.f};

  int rdo = (lane & 15) * 64 + ((((lane >> 4) & 3) << 4) ^ ((((lane & 15) >> 1) & 3) << 4));

  auto stage = [&](int buf) {
    ushort* lb = &AB[buf * 16384];
    gload_lds16(ag0, lb + ldsA0); ag0 += BK;
    gload_lds16(ag1, lb + ldsA1); ag1 += BK;
    gload_lds16(bg0, lb + ldsB0); bg0 += BK;
    gload_lds16(bg1, lb + ldsB1); bg1 += BK;
  };
  auto compute = [&](int buf) {
    const char* base = (const char*)AB + (size_t)buf * 32768;
    bf16x8 a[8], b[4];
#pragma unroll
    for (int mi = 0; mi < 8; ++mi)
      a[mi] = *(const bf16x8*)(base + (wm + mi * 16) * 64 + rdo);
#pragma unroll
    for (int ni = 0; ni < 4; ++ni)
      b[ni] = *(const bf16x8*)(base + 16384 + (wn + ni * 16) * 64 + rdo);
#pragma unroll
    for (int mi = 0; mi < 8; ++mi)
#pragma unroll
      for (int ni = 0; ni < 4; ++ni)
        acc[mi][ni] = __builtin_amdgcn_mfma_f32_16x16x32_bf16(a[mi], b[ni], acc[mi][ni], 0, 0, 0);
  };

  const int T = HID / BK;  // 64, divisible by 4
  stage(0); stage(1); stage(2);
  for (int t4 = 0; t4 < T - 4; t4 += 4) {
    WAITV(8); PBAR(); stage(3); compute(0);
    WAITV(8); PBAR(); stage(0); compute(1);
    WAITV(8); PBAR(); stage(1); compute(2);
    WAITV(8); PBAR(); stage(2); compute(3);
  }
  WAITV(8); PBAR(); stage(3); compute(0);
  WAITV(8); PBAR(); compute(1);
  WAITV(4); PBAR(); compute(2);
  WAITV(0); PBAR(); compute(3);

  int ln = lane & 15, lg4 = (lane >> 4) * 4;
#pragma unroll
  for (int ni = 0; ni < 4; ++ni) {
    int col = nt * 256 + wn + ni * 16 + ln;
    float bias = b2[(size_t)e * DIM + col];
#pragma unroll
    for (int mi = 0; mi < 8; ++mi) {
#pragma unroll
      for (int rg = 0; rg < 4; ++rg) {
        int rl = wm + mi * 16 + lg4 + rg;
        int r = mt * 256 + rl;
        if (r < cn) {
          float v = gts[rl] * (acc[mi][ni][rg] + bias);
          atomicAdd(&out[(size_t)toks[rl] * DIM + col], v);
        }
      }
    }
  }
}

extern "C" void kernel_launch(void* const* d_in, const int* in_sizes, int n_in,
                              void* d_out, int out_size, void* d_ws, size_t ws_size,
                              hipStream_t stream) {
  const float* x  = (const float*)d_in[0];
  const float* rw = (const float*)d_in[1];
  const float* rb = (const float*)d_in[2];
  const float* w1 = (const float*)d_in[3];
  const float* b1 = (const float*)d_in[4];
  const float* w2 = (const float*)d_in[5];
  const float* b2 = (const float*)d_in[6];
  float* out = (float*)d_out;
  char* ws = (char*)d_ws;

  const size_t o_ctrl = 0;
  const size_t o_toke = 256;
  const size_t o_tokg = o_toke + 131072;
  const size_t o_stok = o_tokg + 131072;
  const size_t o_sgat = o_stok + 131072;
  const size_t o_xb   = o_sgat + 131072;
  const size_t o_w1T  = o_xb + (size_t)N_TOK * DIM * 2;
  const size_t o_h    = o_w1T + (size_t)NEXP * HID * DIM * 2;
  const size_t required = o_h + (size_t)N_TOK * 2 * HID * 2;  // ~202 MB
  if (ws_size < required) {
    fprintf(stderr, "kernel_launch: ws too small: have %zu need %zu\n", ws_size, required);
    return;
  }
  int* cnt        = (int*)(ws + o_ctrl);
  int* cursor     = cnt + 8;
  int* offs       = cnt + 16;
  int* tok_e      = (int*)(ws + o_toke);
  float* tok_g    = (float*)(ws + o_tokg);
  int* slot_token = (int*)(ws + o_stok);
  float* slot_gate= (float*)(ws + o_sgat);
  ushort* xb      = (ushort*)(ws + o_xb);
  ushort* w2T     = (ushort*)(ws + o_xb);   // aliased with xb (xb dead after gemm1)
  ushort* w1T     = (ushort*)(ws + o_w1T);
  ushort* hbuf    = (ushort*)(ws + o_h);

  hipMemsetAsync(d_out, 0, (size_t)out_size * 4, stream);
  hipMemsetAsync(ws + o_ctrl, 0, 64, stream);

  xcvt_kernel<<<N_TOK * DIM / 8 / 256, 256, 0, stream>>>(x, xb);
  transpose_cvt<DIM, HID><<<dim3(HID / 64, DIM / 64, NEXP), 256, 0, stream>>>(w1, w1T);

  router_kernel<<<N_TOK / 16, 256, 0, stream>>>(x, rw, rb, cnt, tok_e, tok_g);
  scan_kernel<<<1, 64, 0, stream>>>(cnt, offs, cursor);
  gather_kernel<<<N_TOK / 256, 256, 0, stream>>>(tok_e, tok_g, cursor, slot_token, slot_gate);

  gemm1_kernel<<<8 * 64 * NEXP, 512, 0, stream>>>(xb, w1T, b1, offs, slot_token, hbuf);

  transpose_cvt<HID, DIM><<<dim3(DIM / 64, HID / 64, NEXP), 256, 0, stream>>>(w2, w2T);

  gemm2_kernel<<<4 * 64 * NEXP, 512, 0, stream>>>(hbuf, w2T, b2, offs, slot_token, slot_gate, out);
}

// Round 5
// 652.565 us; speedup vs baseline: 2.0093x; 1.7158x over previous
//
#include <hip/hip_runtime.h>
#include <cstdio>
#include <cstdint>

#define N_TOK 16384
#define DIM   1024
#define NEXP  8
#define HID   2048
#define BK    32

typedef __attribute__((ext_vector_type(8))) short bf16x8;
typedef __attribute__((ext_vector_type(4))) float f32x4;

__device__ inline ushort f2bf(float f) {
  uint32_t u = __float_as_uint(f);
  uint32_t r = (u + 0x7fffu + ((u >> 16) & 1u)) >> 16;
  return (ushort)r;
}

// async global->LDS, 16B per lane; LDS dest is wave-uniform base + lane*16
__device__ __forceinline__ void gload_lds16(const void* g, void* l) {
  __builtin_amdgcn_global_load_lds((const __attribute__((address_space(1))) void*)g,
                                   (__attribute__((address_space(3))) void*)l, 16, 0, 0);
}

// ---------------- x f32 -> bf16 pre-convert ----------------
__global__ __launch_bounds__(256) void xcvt_kernel(const float* __restrict__ x,
                                                   ushort* __restrict__ xb) {
  size_t i = (size_t)blockIdx.x * 256 + threadIdx.x;
  float4 v0 = *(const float4*)(x + i * 8);
  float4 v1 = *(const float4*)(x + i * 8 + 4);
  ushort4 a = { f2bf(v0.x), f2bf(v0.y), f2bf(v0.z), f2bf(v0.w) };
  ushort4 b = { f2bf(v1.x), f2bf(v1.y), f2bf(v1.z), f2bf(v1.w) };
  *(ushort4*)(xb + i * 8) = a;
  *(ushort4*)(xb + i * 8 + 4) = b;
}

// ---------------- router: fp32 logits, top-2; per-block histogram (NO global atomics) ------
__global__ __launch_bounds__(256) void router_kernel(
    const float* __restrict__ x, const float* __restrict__ rw,
    const float* __restrict__ rb, int* __restrict__ blkcnt,
    int* __restrict__ tok_e, float* __restrict__ tok_g) {
  __shared__ float wT[NEXP][DIM];
  __shared__ int hist[NEXP];
  if (threadIdx.x < NEXP) hist[threadIdx.x] = 0;
  for (int i = threadIdx.x; i < NEXP * DIM; i += 256) {
    int d = i >> 3, e = i & 7;
    wT[e][d] = rw[i];
  }
  __syncthreads();
  int wave = threadIdx.x >> 6, lane = threadIdx.x & 63;
  int t0 = blockIdx.x * 16 + wave * 4;
#pragma unroll
  for (int it = 0; it < 4; ++it) {
    int t = t0 + it;
    const float* xr = x + (size_t)t * DIM;
    float acc[NEXP];
#pragma unroll
    for (int e = 0; e < NEXP; ++e) acc[e] = 0.f;
#pragma unroll
    for (int j = 0; j < DIM / 64; ++j) {
      int d = lane + j * 64;
      float xv = xr[d];
#pragma unroll
      for (int e = 0; e < NEXP; ++e) acc[e] += xv * wT[e][d];
    }
    float lg[NEXP];
#pragma unroll
    for (int e = 0; e < NEXP; ++e) {
      float v = acc[e];
      for (int o = 32; o > 0; o >>= 1) v += __shfl_xor(v, o);
      lg[e] = v + rb[e];
    }
    int i0 = 0; float m0 = lg[0];
#pragma unroll
    for (int e = 1; e < NEXP; ++e) if (lg[e] > m0) { m0 = lg[e]; i0 = e; }
    int i1 = -1; float m1 = -3.4e38f;
#pragma unroll
    for (int e = 0; e < NEXP; ++e) if (e != i0 && lg[e] > m1) { m1 = lg[e]; i1 = e; }
    float g0 = 1.f / (1.f + expf(m1 - m0));
    float g1 = 1.f - g0;
    if (lane == 0) {
      tok_e[2 * t] = i0; tok_e[2 * t + 1] = i1;
      tok_g[2 * t] = g0; tok_g[2 * t + 1] = g1;
      atomicAdd(&hist[i0], 1); atomicAdd(&hist[i1], 1);  // LDS atomics, on-chip
    }
  }
  __syncthreads();
  if (threadIdx.x < NEXP) blkcnt[blockIdx.x * NEXP + threadIdx.x] = hist[threadIdx.x];
}

// ---------------- scan: blkcnt[1024][8] -> offs[9], blkbase[1024][8] (64 lanes) ----------
__global__ __launch_bounds__(64) void scan_kernel(const int* __restrict__ blkcnt,
                                                  int* __restrict__ blkbase,
                                                  int* __restrict__ offs) {
  int lane = threadIdx.x;
  int e = lane & 7, chunk = lane >> 3;   // 8 chunks x 128 blocks
  int b0 = chunk * 128;
  int csum = 0;
#pragma unroll 8
  for (int b = 0; b < 128; ++b) csum += blkcnt[(b0 + b) * 8 + e];
  int excl = 0, tot = 0;
#pragma unroll
  for (int j = 0; j < 8; ++j) {
    int v = __shfl(csum, e + 8 * j);
    if (j < chunk) excl += v;
    tot += v;
  }
  int off_e = 0, totsum = 0;
#pragma unroll
  for (int j = 0; j < 8; ++j) {
    int v = __shfl(tot, j);   // lane j holds expert j (chunk 0)
    if (j < e) off_e += v;
    totsum += v;
  }
  if (chunk == 0) offs[e] = off_e;
  if (lane == 0) offs[8] = totsum;
  int base = off_e + excl;
  for (int b = 0; b < 128; ++b) {
    int idx = (b0 + b) * 8 + e;
    blkbase[idx] = base;
    base += blkcnt[idx];
  }
}

// ---------------- gather: slot lists via per-block LDS cursors ----------------
__global__ __launch_bounds__(64) void gather_kernel(
    const int* __restrict__ tok_e, const float* __restrict__ tok_g,
    const int* __restrict__ blkbase, int* __restrict__ slot_token,
    float* __restrict__ slot_gate) {
  __shared__ int lcnt[NEXP];
  int tid = threadIdx.x, blk = blockIdx.x;   // 1024 blocks x 16 tokens
  if (tid < NEXP) lcnt[tid] = blkbase[blk * NEXP + tid];
  __syncthreads();
  if (tid < 32) {
    int t = blk * 16 + (tid >> 1);
    int k = tid & 1;
    int e = tok_e[2 * t + k];
    int s = atomicAdd(&lcnt[e], 1);   // LDS atomic
    slot_token[s] = t;
    slot_gate[s] = tok_g[2 * t + k];
  }
}

// ---------------- transpose + f32->bf16 convert (per expert) ----------------
template <int R, int C>
__global__ __launch_bounds__(256) void transpose_cvt(const float* __restrict__ src,
                                                     ushort* __restrict__ dst) {
  __shared__ float tile[64][65];
  int e = blockIdx.z;
  const float* s = src + (size_t)e * R * C;
  ushort* d = dst + (size_t)e * R * C;
  int r0 = blockIdx.y * 64, c0 = blockIdx.x * 64;
#pragma unroll
  for (int i = 0; i < 16; ++i) {
    int idx = i * 256 + threadIdx.x;
    int r = idx >> 6, c = idx & 63;
    tile[r][c] = s[(size_t)(r0 + r) * C + c0 + c];
  }
  __syncthreads();
#pragma unroll
  for (int i = 0; i < 16; ++i) {
    int idx = i * 256 + threadIdx.x;
    int orow = idx >> 6, oc = idx & 63;
    d[(size_t)(c0 + orow) * R + r0 + oc] = f2bf(tile[oc][orow]);
  }
}

// =============== 256x256 grouped GEMM, 8 waves, BK=32, 4-buf depth-3 pipeline ===============
#define WAITV(N) asm volatile("s_waitcnt vmcnt(" #N ")" ::: "memory")
#define PBAR()  do { __builtin_amdgcn_s_barrier(); __builtin_amdgcn_sched_barrier(0); } while (0)

// gemm1: h = relu(x_gather @ w1T^T + b1)   K = DIM -> T = 32 tiles
__global__ __launch_bounds__(512, 2) void gemm1_kernel(
    const ushort* __restrict__ xb, const ushort* __restrict__ w1T,
    const float* __restrict__ b1, const int* __restrict__ offs,
    const int* __restrict__ slot_token, ushort* __restrict__ h) {
  int flat = blockIdx.x;                     // nwg = 8*64*8 = 4096
  int swz = (flat & 7) * 512 + (flat >> 3);  // XCD x -> expert x
  int e = swz >> 9;
  int rem = swz & 511;
  int mt = rem >> 3;
  int nt = rem & 7;
  int off = offs[e];
  int cn = offs[e + 1] - off;
  if (mt * 256 >= cn) return;

  __shared__ __align__(16) ushort AB[4 * 16384];  // 128 KB
  __shared__ int toks[256];
  int tid = threadIdx.x;
  if (tid < 256) {
    int r = mt * 256 + tid;
    toks[tid] = slot_token[off + (r < cn ? r : 0)];
  }
  __syncthreads();
  int wave = tid >> 6, lane = tid & 63;
  int wm = (wave >> 2) * 128, wn = (wave & 3) * 64;

  const ushort* Bsrc = w1T + (size_t)e * HID * DIM + (size_t)(nt * 256) * DIM;
  int colsw = ((lane & 3) ^ ((lane >> 3) & 3)) * 8;  // pre-swizzled source col (elems)
  int r0 = wave * 16 + (lane >> 2);
  const ushort* ag0 = xb + (size_t)toks[r0] * DIM + colsw;
  const ushort* ag1 = xb + (size_t)toks[128 + r0] * DIM + colsw;
  const ushort* bg0 = Bsrc + (size_t)r0 * DIM + colsw;
  const ushort* bg1 = Bsrc + (size_t)(128 + r0) * DIM + colsw;
  int ldsA0 = (wave * 16) * BK;
  int ldsA1 = (128 + wave * 16) * BK;
  int ldsB0 = 8192 + ldsA0;
  int ldsB1 = 8192 + ldsA1;

  f32x4 acc[8][4];
#pragma unroll
  for (int i = 0; i < 8; ++i)
#pragma unroll
    for (int j = 0; j < 4; ++j) acc[i][j] = (f32x4){0.f, 0.f, 0.f, 0.f};

  int rdo = (lane & 15) * 64 + ((((lane >> 4) & 3) << 4) ^ ((((lane & 15) >> 1) & 3) << 4));

  auto stage = [&](int buf) {
    ushort* lb = &AB[buf * 16384];
    gload_lds16(ag0, lb + ldsA0); ag0 += BK;
    gload_lds16(ag1, lb + ldsA1); ag1 += BK;
    gload_lds16(bg0, lb + ldsB0); bg0 += BK;
    gload_lds16(bg1, lb + ldsB1); bg1 += BK;
  };
  auto compute = [&](int buf) {
    const char* base = (const char*)AB + (size_t)buf * 32768;
    bf16x8 a[8], b[4];
#pragma unroll
    for (int mi = 0; mi < 8; ++mi)
      a[mi] = *(const bf16x8*)(base + (wm + mi * 16) * 64 + rdo);
#pragma unroll
    for (int ni = 0; ni < 4; ++ni)
      b[ni] = *(const bf16x8*)(base + 16384 + (wn + ni * 16) * 64 + rdo);
#pragma unroll
    for (int mi = 0; mi < 8; ++mi)
#pragma unroll
      for (int ni = 0; ni < 4; ++ni)
        acc[mi][ni] = __builtin_amdgcn_mfma_f32_16x16x32_bf16(a[mi], b[ni], acc[mi][ni], 0, 0, 0);
  };

  const int T = DIM / BK;  // 32
  stage(0); stage(1); stage(2);
  for (int t4 = 0; t4 < T - 4; t4 += 4) {
    WAITV(8); PBAR(); stage(3); compute(0);
    WAITV(8); PBAR(); stage(0); compute(1);
    WAITV(8); PBAR(); stage(1); compute(2);
    WAITV(8); PBAR(); stage(2); compute(3);
  }
  WAITV(8); PBAR(); stage(3); compute(0);
  WAITV(8); PBAR(); compute(1);
  WAITV(4); PBAR(); compute(2);
  WAITV(0); PBAR(); compute(3);

  int ln = lane & 15, lg4 = (lane >> 4) * 4;
#pragma unroll
  for (int ni = 0; ni < 4; ++ni) {
    int col = nt * 256 + wn + ni * 16 + ln;
    float bias = b1[(size_t)e * HID + col];
#pragma unroll
    for (int mi = 0; mi < 8; ++mi) {
#pragma unroll
      for (int rg = 0; rg < 4; ++rg) {
        int r = mt * 256 + wm + mi * 16 + lg4 + rg;
        if (r < cn) {
          float v = acc[mi][ni][rg] + bias;
          h[(size_t)(off + r) * HID + col] = f2bf(fmaxf(v, 0.f));
        }
      }
    }
  }
}

// gemm2: out[token] += gate * (h @ w2T^T + b2)   K = HID -> T = 64 tiles
__global__ __launch_bounds__(512, 2) void gemm2_kernel(
    const ushort* __restrict__ h, const ushort* __restrict__ w2T,
    const float* __restrict__ b2, const int* __restrict__ offs,
    const int* __restrict__ slot_token, const float* __restrict__ slot_gate,
    float* __restrict__ out) {
  int flat = blockIdx.x;                     // nwg = 4*64*8 = 2048
  int swz = (flat & 7) * 256 + (flat >> 3);  // XCD x -> expert x
  int e = swz >> 8;
  int rem = swz & 255;
  int mt = rem >> 2;
  int nt = rem & 3;
  int off = offs[e];
  int cn = offs[e + 1] - off;
  if (mt * 256 >= cn) return;

  __shared__ __align__(16) ushort AB[4 * 16384];  // 128 KB
  __shared__ int toks[256];
  __shared__ float gts[256];
  int tid = threadIdx.x;
  if (tid < 256) {
    int r = mt * 256 + tid;
    int s = off + (r < cn ? r : 0);
    toks[tid] = slot_token[s];
    gts[tid] = slot_gate[s];
  }
  __syncthreads();
  int wave = tid >> 6, lane = tid & 63;
  int wm = (wave >> 2) * 128, wn = (wave & 3) * 64;

  const ushort* Bsrc = w2T + (size_t)e * DIM * HID + (size_t)(nt * 256) * HID;
  int colsw = ((lane & 3) ^ ((lane >> 3) & 3)) * 8;
  int r0 = wave * 16 + (lane >> 2);
  int ra0 = mt * 256 + r0;       ra0 = ra0 < cn ? ra0 : 0;
  int ra1 = mt * 256 + 128 + r0; ra1 = ra1 < cn ? ra1 : 0;
  const ushort* ag0 = h + (size_t)(off + ra0) * HID + colsw;
  const ushort* ag1 = h + (size_t)(off + ra1) * HID + colsw;
  const ushort* bg0 = Bsrc + (size_t)r0 * HID + colsw;
  const ushort* bg1 = Bsrc + (size_t)(128 + r0) * HID + colsw;
  int ldsA0 = (wave * 16) * BK;
  int ldsA1 = (128 + wave * 16) * BK;
  int ldsB0 = 8192 + ldsA0;
  int ldsB1 = 8192 + ldsA1;

  f32x4 acc[8][4];
#pragma unroll
  for (int i = 0; i < 8; ++i)
#pragma unroll
    for (int j = 0; j < 4; ++j) acc[i][j] = (f32x4){0.f, 0.f, 0.f, 0.f};

  int rdo = (lane & 15) * 64 + ((((lane >> 4) & 3) << 4) ^ ((((lane & 15) >> 1) & 3) << 4));

  auto stage = [&](int buf) {
    ushort* lb = &AB[buf * 16384];
    gload_lds16(ag0, lb + ldsA0); ag0 += BK;
    gload_lds16(ag1, lb + ldsA1); ag1 += BK;
    gload_lds16(bg0, lb + ldsB0); bg0 += BK;
    gload_lds16(bg1, lb + ldsB1); bg1 += BK;
  };
  auto compute = [&](int buf) {
    const char* base = (const char*)AB + (size_t)buf * 32768;
    bf16x8 a[8], b[4];
#pragma unroll
    for (int mi = 0; mi < 8; ++mi)
      a[mi] = *(const bf16x8*)(base + (wm + mi * 16) * 64 + rdo);
#pragma unroll
    for (int ni = 0; ni < 4; ++ni)
      b[ni] = *(const bf16x8*)(base + 16384 + (wn + ni * 16) * 64 + rdo);
#pragma unroll
    for (int mi = 0; mi < 8; ++mi)
#pragma unroll
      for (int ni = 0; ni < 4; ++ni)
        acc[mi][ni] = __builtin_amdgcn_mfma_f32_16x16x32_bf16(a[mi], b[ni], acc[mi][ni], 0, 0, 0);
  };

  const int T = HID / BK;  // 64
  stage(0); stage(1); stage(2);
  for (int t4 = 0; t4 < T - 4; t4 += 4) {
    WAITV(8); PBAR(); stage(3); compute(0);
    WAITV(8); PBAR(); stage(0); compute(1);
    WAITV(8); PBAR(); stage(1); compute(2);
    WAITV(8); PBAR(); stage(2); compute(3);
  }
  WAITV(8); PBAR(); stage(3); compute(0);
  WAITV(8); PBAR(); compute(1);
  WAITV(4); PBAR(); compute(2);
  WAITV(0); PBAR(); compute(3);

  int ln = lane & 15, lg4 = (lane >> 4) * 4;
#pragma unroll
  for (int ni = 0; ni < 4; ++ni) {
    int col = nt * 256 + wn + ni * 16 + ln;
    float bias = b2[(size_t)e * DIM + col];
#pragma unroll
    for (int mi = 0; mi < 8; ++mi) {
#pragma unroll
      for (int rg = 0; rg < 4; ++rg) {
        int rl = wm + mi * 16 + lg4 + rg;
        int r = mt * 256 + rl;
        if (r < cn) {
          float v = gts[rl] * (acc[mi][ni][rg] + bias);
          atomicAdd(&out[(size_t)toks[rl] * DIM + col], v);
        }
      }
    }
  }
}

extern "C" void kernel_launch(void* const* d_in, const int* in_sizes, int n_in,
                              void* d_out, int out_size, void* d_ws, size_t ws_size,
                              hipStream_t stream) {
  const float* x  = (const float*)d_in[0];
  const float* rw = (const float*)d_in[1];
  const float* rb = (const float*)d_in[2];
  const float* w1 = (const float*)d_in[3];
  const float* b1 = (const float*)d_in[4];
  const float* w2 = (const float*)d_in[5];
  const float* b2 = (const float*)d_in[6];
  float* out = (float*)d_out;
  char* ws = (char*)d_ws;

  const size_t o_ctrl = 0;                    // offs[9] (+pad)
  const size_t o_toke = 256;
  const size_t o_tokg = o_toke + 131072;
  const size_t o_stok = o_tokg + 131072;
  const size_t o_sgat = o_stok + 131072;
  const size_t o_xb   = o_sgat + 131072;
  const size_t o_w1T  = o_xb + (size_t)N_TOK * DIM * 2;
  const size_t o_h    = o_w1T + (size_t)NEXP * HID * DIM * 2;
  const size_t required = o_h + (size_t)N_TOK * 2 * HID * 2;  // ~202 MB
  if (ws_size < required) {
    fprintf(stderr, "kernel_launch: ws too small: have %zu need %zu\n", ws_size, required);
    return;
  }
  int* offs       = (int*)(ws + o_ctrl);
  int* tok_e      = (int*)(ws + o_toke);
  float* tok_g    = (float*)(ws + o_tokg);
  int* slot_token = (int*)(ws + o_stok);
  float* slot_gate= (float*)(ws + o_sgat);
  ushort* xb      = (ushort*)(ws + o_xb);
  ushort* w2T     = (ushort*)(ws + o_xb);   // aliased with xb (xb dead after gemm1)
  ushort* w1T     = (ushort*)(ws + o_w1T);
  ushort* hbuf    = (ushort*)(ws + o_h);
  // blkcnt/blkbase (64 KB) alias the hbuf region: used only BEFORE gemm1 writes h
  int* blkcnt     = (int*)(ws + o_h);
  int* blkbase    = blkcnt + 1024 * NEXP;

  hipMemsetAsync(d_out, 0, (size_t)out_size * 4, stream);
  hipMemsetAsync(ws + o_ctrl, 0, 64, stream);

  xcvt_kernel<<<N_TOK * DIM / 8 / 256, 256, 0, stream>>>(x, xb);
  transpose_cvt<DIM, HID><<<dim3(HID / 64, DIM / 64, NEXP), 256, 0, stream>>>(w1, w1T);

  router_kernel<<<N_TOK / 16, 256, 0, stream>>>(x, rw, rb, blkcnt, tok_e, tok_g);
  scan_kernel<<<1, 64, 0, stream>>>(blkcnt, blkbase, offs);
  gather_kernel<<<N_TOK / 16, 64, 0, stream>>>(tok_e, tok_g, blkbase, slot_token, slot_gate);

  gemm1_kernel<<<8 * 64 * NEXP, 512, 0, stream>>>(xb, w1T, b1, offs, slot_token, hbuf);

  transpose_cvt<HID, DIM><<<dim3(DIM / 64, HID / 64, NEXP), 256, 0, stream>>>(w2, w2T);

  gemm2_kernel<<<4 * 64 * NEXP, 512, 0, stream>>>(hbuf, w2T, b2, offs, slot_token, slot_gate, out);
}